// Round 1
// baseline (422.751 us; speedup 1.0000x reference)
//
#include <hip/hip_runtime.h>
#include <hip/hip_bf16.h>

typedef __attribute__((ext_vector_type(8))) short bf16x8;
typedef __attribute__((ext_vector_type(4))) float f32x4;

#define ANGLE_COS 0.8775825618903728f  // cos(0.5)
#define ANGLE_SIN 0.4794255386042030f  // sin(0.5)

static __device__ __forceinline__ unsigned short f2bf(float x) {
  union { float f; unsigned u; } v; v.f = x;
  unsigned r = v.u + 0x7FFFu + ((v.u >> 16) & 1u);  // RNE
  return (unsigned short)(r >> 16);
}

// ---- column inverse norms of w (D=128 fixed) ----
__global__ void colnorm_kernel(const float* __restrict__ w, float* __restrict__ colinv, int C) {
  int c = blockIdx.x * 256 + threadIdx.x;
  if (c >= C) return;
  float s = 0.f;
  #pragma unroll 8
  for (int d = 0; d < 128; ++d) { float v = w[(size_t)d * C + c]; s += v * v; }
  colinv[c] = 1.0f / sqrtf(s);
}

// ---- row-normalize features -> bf16 Fn, store inverse norms ----
__global__ void fnorm_kernel(const float* __restrict__ f, unsigned short* __restrict__ Fn,
                             float* __restrict__ rowinv) {
  const int wave = threadIdx.x >> 6, lane = threadIdx.x & 63;
  const int row = blockIdx.x * 4 + wave;
  const float* fr = f + (size_t)row * 128;
  float x0 = fr[lane], x1 = fr[lane + 64];
  float s = x0 * x0 + x1 * x1;
  #pragma unroll
  for (int m = 32; m; m >>= 1) s += __shfl_xor(s, m);
  float inv = 1.0f / sqrtf(s);
  Fn[(size_t)row * 128 + lane] = f2bf(x0 * inv);
  Fn[(size_t)row * 128 + lane + 64] = f2bf(x1 * inv);
  if (lane == 0) rowinv[row] = inv;
}

// ---- fp32 dot with the target column: ct and cos(theta+m) per row ----
__global__ void tgtdot_kernel(const float* __restrict__ f, const float* __restrict__ w,
                              const int* __restrict__ target, const float* __restrict__ rowinv,
                              const float* __restrict__ colinv, float* __restrict__ ctv,
                              float* __restrict__ cpv, int C) {
  const int wave = threadIdx.x >> 6, lane = threadIdx.x & 63;
  const int row = blockIdx.x * 4 + wave;
  const int t = target[row];
  const float* fr = f + (size_t)row * 128;
  float s = fr[lane] * w[(size_t)lane * C + t] + fr[lane + 64] * w[(size_t)(lane + 64) * C + t];
  #pragma unroll
  for (int m = 32; m; m >>= 1) s += __shfl_xor(s, m);
  if (lane == 0) {
    float ct = s * rowinv[row] * colinv[t];
    ct = fminf(1.f, fmaxf(-1.f, ct));
    float st = sqrtf(fmaxf(0.f, 1.f - ct * ct));
    ctv[row] = ct;
    cpv[row] = ct * ANGLE_COS - st * ANGLE_SIN;
  }
}

// ---- main: rowsum[i] += sum_c exp( Fn[i,:] @ wn[:,c] ) over this block's tile ----
// Block: 4 waves x 128 rows = 512 rows; 128 cols; K=128. B tile in LDS (bf16,
// XOR-swizzled 16B chunks to break the 256B-stride bank conflict). A persistent
// in registers (128 VGPR) -> 128 FLOP per LDS byte (LDS-balanced vs MFMA).
__global__ __launch_bounds__(256, 2) void arc_main_kernel(
    const float* __restrict__ w, const float* __restrict__ colinv,
    const unsigned short* __restrict__ Fn, float* __restrict__ rowsum, int C) {
  __shared__ __align__(16) unsigned short Bt[128 * 128];
  const int tid = threadIdx.x;
  const int cbase = blockIdx.x << 7;

  // stage B tile: w col-major-ized into LDS, normalized, bf16, swizzled
  {
    const int c = tid & 127;
    const int dstart = tid >> 7;  // 0 or 1
    const int gc = cbase + c;
    const bool ok = (gc < C);
    const float cinv = ok ? colinv[gc] : 0.f;
    const float* wp = w + gc;
    char* bcol = (char*)Bt + c * 256;
    const int swz = (c & 7) << 4;
    #pragma unroll 8
    for (int d = dstart; d < 128; d += 2) {
      float v = ok ? wp[(size_t)d * C] * cinv : 0.f;  // padded cols -> 0 -> exp(0)=1, subtracted later
      *(unsigned short*)(bcol + ((d * 2) ^ swz)) = f2bf(v);
    }
  }

  const int wave = tid >> 6;
  const int lane = tid & 63;
  const int l15 = lane & 15;
  const int lhi = lane >> 4;
  const int rowbase = blockIdx.y * 512 + wave * 128;

  // A fragments: 8 row-frags (16 rows) x 4 K-steps, 16B each = 128 VGPR
  bf16x8 a[8][4];
  {
    const char* base = (const char*)Fn + (size_t)(rowbase + l15) * 256 + lhi * 16;
    #pragma unroll
    for (int rf = 0; rf < 8; ++rf)
      #pragma unroll
      for (int s = 0; s < 4; ++s)
        a[rf][s] = *(const bf16x8*)(base + rf * 16 * 256 + s * 64);
  }

  __syncthreads();

  float psum[8][4];
  #pragma unroll
  for (int rf = 0; rf < 8; ++rf)
    #pragma unroll
    for (int r = 0; r < 4; ++r) psum[rf][r] = 0.f;

  #pragma unroll
  for (int cf = 0; cf < 8; ++cf) {
    const int col = cf * 16 + l15;
    const char* bcol = (const char*)Bt + col * 256;
    const int swz = (col & 7) << 4;
    f32x4 acc[8];
    #pragma unroll
    for (int rf = 0; rf < 8; ++rf) acc[rf] = (f32x4){0.f, 0.f, 0.f, 0.f};
    #pragma unroll
    for (int s = 0; s < 4; ++s) {
      bf16x8 bfrag = *(const bf16x8*)(bcol + ((lhi * 16 + s * 64) ^ swz));
      #pragma unroll
      for (int rf = 0; rf < 8; ++rf)
        acc[rf] = __builtin_amdgcn_mfma_f32_16x16x32_bf16(a[rf][s], bfrag, acc[rf], 0, 0, 0);
    }
    // D layout (verified m89): col = lane&15, row = (lane>>4)*4 + reg
    #pragma unroll
    for (int rf = 0; rf < 8; ++rf)
      #pragma unroll
      for (int r = 0; r < 4; ++r)
        psum[rf][r] += __expf(acc[rf][r]);
  }

  // reduce across the 16 lanes (cols) sharing each row, then one atomic per row
  #pragma unroll
  for (int rf = 0; rf < 8; ++rf)
    #pragma unroll
    for (int r = 0; r < 4; ++r) {
      float v = psum[rf][r];
      v += __shfl_xor(v, 1);
      v += __shfl_xor(v, 2);
      v += __shfl_xor(v, 4);
      v += __shfl_xor(v, 8);
      if (l15 == 0) atomicAdd(&rowsum[rowbase + rf * 16 + lhi * 4 + r], v);
    }
}

// ---- finalize: loss = mean( log(down_i) - cosplus_i ) ----
__global__ void finalize_kernel(const float* __restrict__ rowsum, const float* __restrict__ ctv,
                                const float* __restrict__ cpv, float* __restrict__ out,
                                int N, float pad, float invN) {
  const int tid = threadIdx.x;
  float local = 0.f;
  for (int i = tid; i < N; i += 256) {
    float top = __expf(cpv[i]);
    float down = rowsum[i] - pad - __expf(ctv[i]) + top;
    local += __logf(down) - cpv[i];
  }
  #pragma unroll
  for (int m = 32; m; m >>= 1) local += __shfl_xor(local, m);
  __shared__ float red[4];
  if ((tid & 63) == 0) red[tid >> 6] = local;
  __syncthreads();
  if (tid == 0) out[0] = (red[0] + red[1] + red[2] + red[3]) * invN;
}

extern "C" void kernel_launch(void* const* d_in, const int* in_sizes, int n_in,
                              void* d_out, int out_size, void* d_ws, size_t ws_size,
                              hipStream_t stream) {
  const float* features = (const float*)d_in[0];
  const int* target = (const int*)d_in[1];
  const float* w = (const float*)d_in[2];
  float* out = (float*)d_out;

  const int N = in_sizes[1];          // 2048
  const int D = in_sizes[0] / N;      // 128 (layout hardcoded in kernels)
  const int C = in_sizes[2] / D;      // 100000
  (void)D;

  char* ws = (char*)d_ws;
  size_t off = 0;
  unsigned short* Fn = (unsigned short*)(ws + off); off += (size_t)N * 128 * 2;
  float* colinv = (float*)(ws + off); off += (size_t)C * 4; off = (off + 255) & ~(size_t)255;
  float* rowsum = (float*)(ws + off); off += (size_t)N * 4;
  float* rowinv = (float*)(ws + off); off += (size_t)N * 4;
  float* ctv    = (float*)(ws + off); off += (size_t)N * 4;
  float* cpv    = (float*)(ws + off); off += (size_t)N * 4;

  hipMemsetAsync(rowsum, 0, (size_t)N * sizeof(float), stream);
  colnorm_kernel<<<(C + 255) / 256, 256, 0, stream>>>(w, colinv, C);
  fnorm_kernel<<<N / 4, 256, 0, stream>>>(features, Fn, rowinv);
  tgtdot_kernel<<<N / 4, 256, 0, stream>>>(features, w, target, rowinv, colinv, ctv, cpv, C);

  const int nct = (C + 127) / 128;    // 782 col tiles
  arc_main_kernel<<<dim3(nct, N / 512), 256, 0, stream>>>(w, colinv, Fn, rowsum, C);
  finalize_kernel<<<1, 256, 0, stream>>>(rowsum, ctv, cpv, out, N,
                                         (float)(nct * 128 - C), 1.0f / (float)N);
}

// Round 2
// 299.960 us; speedup vs baseline: 1.4094x; 1.4094x over previous
//
#include <hip/hip_runtime.h>
#include <hip/hip_bf16.h>

typedef __attribute__((ext_vector_type(8))) short bf16x8;
typedef __attribute__((ext_vector_type(4))) float f32x4;

#define ANGLE_COS 0.8775825618903728f  // cos(0.5)
#define ANGLE_SIN 0.4794255386042030f  // sin(0.5)

static __device__ __forceinline__ unsigned short f2bf(float x) {
  union { float f; unsigned u; } v; v.f = x;
  unsigned r = v.u + 0x7FFFu + ((v.u >> 16) & 1u);  // RNE
  return (unsigned short)(r >> 16);
}

// ---- column inverse norms of w (D=128 fixed) ----
__global__ void colnorm_kernel(const float* __restrict__ w, float* __restrict__ colinv, int C) {
  int c = blockIdx.x * 256 + threadIdx.x;
  if (c >= C) return;
  float s = 0.f;
  #pragma unroll 8
  for (int d = 0; d < 128; ++d) { float v = w[(size_t)d * C + c]; s += v * v; }
  colinv[c] = 1.0f / sqrtf(s);
}

// ---- row-normalize features -> bf16 Fn, store inverse norms ----
__global__ void fnorm_kernel(const float* __restrict__ f, unsigned short* __restrict__ Fn,
                             float* __restrict__ rowinv) {
  const int wave = threadIdx.x >> 6, lane = threadIdx.x & 63;
  const int row = blockIdx.x * 4 + wave;
  const float* fr = f + (size_t)row * 128;
  float x0 = fr[lane], x1 = fr[lane + 64];
  float s = x0 * x0 + x1 * x1;
  #pragma unroll
  for (int m = 32; m; m >>= 1) s += __shfl_xor(s, m);
  float inv = 1.0f / sqrtf(s);
  Fn[(size_t)row * 128 + lane] = f2bf(x0 * inv);
  Fn[(size_t)row * 128 + lane + 64] = f2bf(x1 * inv);
  if (lane == 0) rowinv[row] = inv;
}

// ---- fp32 dot with the target column: ct and cos(theta+m) per row ----
__global__ void tgtdot_kernel(const float* __restrict__ f, const float* __restrict__ w,
                              const int* __restrict__ target, const float* __restrict__ rowinv,
                              const float* __restrict__ colinv, float* __restrict__ ctv,
                              float* __restrict__ cpv, int C) {
  const int wave = threadIdx.x >> 6, lane = threadIdx.x & 63;
  const int row = blockIdx.x * 4 + wave;
  const int t = target[row];
  const float* fr = f + (size_t)row * 128;
  float s = fr[lane] * w[(size_t)lane * C + t] + fr[lane + 64] * w[(size_t)(lane + 64) * C + t];
  #pragma unroll
  for (int m = 32; m; m >>= 1) s += __shfl_xor(s, m);
  if (lane == 0) {
    float ct = s * rowinv[row] * colinv[t];
    ct = fminf(1.f, fmaxf(-1.f, ct));
    float st = sqrtf(fmaxf(0.f, 1.f - ct * ct));
    ctv[row] = ct;
    cpv[row] = ct * ANGLE_COS - st * ANGLE_SIN;
  }
}

// ---- main: per block: stage 128 cols of wn (bf16) in LDS once, loop over ALL
// rows in 512-row groups (A-frags from L2-resident Fn), accumulate
// exp(f@wn) row-sums, write per-block partials (no device atomics).
// LDS layout: 16B chunk (d-block q=d>>3, col): addr = q*2048 + col*16 + (d&7)*2.
//   reads: bank-group = col&7 -> 8 groups x 8 lanes = conflict-free.
//   writes: scalar b16 spread over 8 banks (~free per m136).
template <int USE_ATOMIC>
__global__ __launch_bounds__(256) void arc_main_kernel(
    const float* __restrict__ w, const float* __restrict__ colinv,
    const unsigned short* __restrict__ Fn, float* __restrict__ out_part,
    int C, int nrows) {
  __shared__ __align__(16) unsigned short Bt[128 * 128];
  const int tid = threadIdx.x;
  const int bx = blockIdx.x;
  const int cbase = bx << 7;

  // ---- stage B tile (128 cols x 128 d), normalized bf16 ----
  {
    const int c = tid & 127;
    const int gc = cbase + c;
    const bool ok = (gc < C);
    const float cinv = ok ? colinv[gc] : 0.f;
    const float* wp = w + (size_t)(tid >> 7) * C + gc;
    char* lb = (char*)Bt + c * 16;
    #pragma unroll 16
    for (int s = 0; s < 64; ++s) {
      const int d = (tid >> 7) + 2 * s;
      float v = ok ? wp[(size_t)(2 * s) * C] : 0.f;
      *(unsigned short*)(lb + ((d >> 3) * 2048 + (d & 7) * 2)) = f2bf(v * cinv);
    }
  }
  __syncthreads();

  const int wave = tid >> 6;
  const int lane = tid & 63;
  const int l15 = lane & 15;
  const int lhi = lane >> 4;
  const int ngroups = nrows >> 9;  // 512 rows per group

  for (int g = 0; g < ngroups; ++g) {
    const int rowbase = g * 512 + wave * 128;

    // A fragments: 8 row-frags (16 rows) x 4 K-steps, 16B each = 128 VGPR
    bf16x8 a[8][4];
    {
      const char* base = (const char*)Fn + (size_t)(rowbase + l15) * 256 + lhi * 16;
      #pragma unroll
      for (int rf = 0; rf < 8; ++rf)
        #pragma unroll
        for (int s = 0; s < 4; ++s)
          a[rf][s] = *(const bf16x8*)(base + rf * 16 * 256 + s * 64);
    }

    float psum[8][4];
    #pragma unroll
    for (int rf = 0; rf < 8; ++rf)
      #pragma unroll
      for (int r = 0; r < 4; ++r) psum[rf][r] = 0.f;

    #pragma unroll
    for (int cf = 0; cf < 8; ++cf) {
      const char* bcol = (const char*)Bt + (cf * 16 + l15) * 16;
      f32x4 acc[8];
      #pragma unroll
      for (int rf = 0; rf < 8; ++rf) acc[rf] = (f32x4){0.f, 0.f, 0.f, 0.f};
      #pragma unroll
      for (int s = 0; s < 4; ++s) {
        bf16x8 bfrag = *(const bf16x8*)(bcol + (s * 4 + lhi) * 2048);
        #pragma unroll
        for (int rf = 0; rf < 8; ++rf)
          acc[rf] = __builtin_amdgcn_mfma_f32_16x16x32_bf16(a[rf][s], bfrag, acc[rf], 0, 0, 0);
      }
      // D layout (verified): col = lane&15, row = (lane>>4)*4 + reg
      #pragma unroll
      for (int rf = 0; rf < 8; ++rf)
        #pragma unroll
        for (int r = 0; r < 4; ++r)
          psum[rf][r] += __expf(acc[rf][r]);
    }

    // reduce across the 16 lanes (cols) sharing each row
    #pragma unroll
    for (int rf = 0; rf < 8; ++rf)
      #pragma unroll
      for (int r = 0; r < 4; ++r) {
        float v = psum[rf][r];
        v += __shfl_xor(v, 1);
        v += __shfl_xor(v, 2);
        v += __shfl_xor(v, 4);
        v += __shfl_xor(v, 8);
        if (l15 == 0) {
          const int row = rowbase + rf * 16 + lhi * 4 + r;
          if (USE_ATOMIC) atomicAdd(&out_part[row], v);
          else out_part[(size_t)bx * nrows + row] = v;
        }
      }
  }
}

// ---- combine partials: 8 row-blocks x 8 part-slices ----
__global__ void reduce_kernel(const float* __restrict__ partial, float* __restrict__ rowsum,
                              int nparts, int nrows) {
  const int row = (blockIdx.x & 7) * 256 + threadIdx.x;
  const int slice = blockIdx.x >> 3;
  const int pper = (nparts + 7) / 8;
  const int p0 = slice * pper;
  const int p1 = min(nparts, p0 + pper);
  float s = 0.f;
  #pragma unroll 4
  for (int p = p0; p < p1; ++p) s += partial[(size_t)p * nrows + row];
  atomicAdd(&rowsum[row], s);
}

// ---- finalize: loss = mean( log(down_i) - cosplus_i ) ----
__global__ void finalize_kernel(const float* __restrict__ rowsum, const float* __restrict__ ctv,
                                const float* __restrict__ cpv, float* __restrict__ out,
                                int N, float pad, float invN) {
  const int tid = threadIdx.x;
  float local = 0.f;
  for (int i = tid; i < N; i += 256) {
    float top = __expf(cpv[i]);
    float down = rowsum[i] - pad - __expf(ctv[i]) + top;
    local += __logf(down) - cpv[i];
  }
  #pragma unroll
  for (int m = 32; m; m >>= 1) local += __shfl_xor(local, m);
  __shared__ float red[4];
  if ((tid & 63) == 0) red[tid >> 6] = local;
  __syncthreads();
  if (tid == 0) out[0] = (red[0] + red[1] + red[2] + red[3]) * invN;
}

extern "C" void kernel_launch(void* const* d_in, const int* in_sizes, int n_in,
                              void* d_out, int out_size, void* d_ws, size_t ws_size,
                              hipStream_t stream) {
  const float* features = (const float*)d_in[0];
  const int* target = (const int*)d_in[1];
  const float* w = (const float*)d_in[2];
  float* out = (float*)d_out;

  const int N = in_sizes[1];          // 2048
  const int D = in_sizes[0] / N;      // 128 (layout hardcoded in kernels)
  const int C = in_sizes[2] / D;      // 100000
  (void)D;
  const int nct = (C + 127) / 128;    // 782 col tiles

  char* ws = (char*)d_ws;
  size_t off = 0;
  unsigned short* Fn = (unsigned short*)(ws + off); off += (size_t)N * 128 * 2;
  float* colinv = (float*)(ws + off); off += (size_t)C * 4; off = (off + 255) & ~(size_t)255;
  float* rowsum = (float*)(ws + off); off += (size_t)N * 4;
  float* rowinv = (float*)(ws + off); off += (size_t)N * 4;
  float* ctv    = (float*)(ws + off); off += (size_t)N * 4;
  float* cpv    = (float*)(ws + off); off += (size_t)N * 4; off = (off + 255) & ~(size_t)255;
  float* partial = (float*)(ws + off);
  const size_t need = off + (size_t)nct * N * 4;
  const bool use_store = (ws_size >= need);

  hipMemsetAsync(rowsum, 0, (size_t)N * sizeof(float), stream);
  colnorm_kernel<<<(C + 255) / 256, 256, 0, stream>>>(w, colinv, C);
  fnorm_kernel<<<N / 4, 256, 0, stream>>>(features, Fn, rowinv);
  tgtdot_kernel<<<N / 4, 256, 0, stream>>>(features, w, target, rowinv, colinv, ctv, cpv, C);

  if (use_store) {
    arc_main_kernel<0><<<nct, 256, 0, stream>>>(w, colinv, Fn, partial, C, N);
    reduce_kernel<<<64, 256, 0, stream>>>(partial, rowsum, nct, N);
  } else {
    arc_main_kernel<1><<<nct, 256, 0, stream>>>(w, colinv, Fn, rowsum, C, N);
  }
  finalize_kernel<<<1, 256, 0, stream>>>(rowsum, ctv, cpv, out, N,
                                         (float)(nct * 128 - C), 1.0f / (float)N);
}